// Round 1
// baseline (113.689 us; speedup 1.0000x reference)
//
#include <hip/hip_runtime.h>
#include <hip/hip_bf16.h>
#include <math.h>

// Problem constants
#define N_TOK 16384
#define I_DIM 128
#define O_DIM 128
#define G_DIM 16
// GEMM tiling
#define BN 64          // n-rows per block
#define CI 4           // i-values per K-chunk
#define KC (CI * G_DIM * 2)       // 128 k per chunk
#define NCHUNK (I_DIM / CI)       // 32 chunks
#define A_STRIDE 136   // bf16 elems per LDS A row (272 B, padded vs 256)
#define B_STRIDE 136   // bf16 elems per LDS B row
#define C_STRIDE 132   // floats per LDS C row

typedef __bf16 bf16x8 __attribute__((ext_vector_type(8)));
typedef float  f32x4  __attribute__((ext_vector_type(4)));

// ---------------------------------------------------------------------------
// Pack cos/sin amplitudes (O,I,G) fp32 -> bf16 Bpack[chunk][o][kk]
// kk = il*32 + g*2 + s   (il = i within chunk, s: 0=cos 1=sin)
// ---------------------------------------------------------------------------
__global__ __launch_bounds__(256) void fkan_pack_b(
    const float* __restrict__ cosA, const float* __restrict__ sinA,
    __hip_bfloat16* __restrict__ Bp)
{
    int idx = blockIdx.x * 256 + threadIdx.x;       // 0 .. 32*128*128-1
    int kk = idx & 127;
    int o  = (idx >> 7) & 127;
    int c  = idx >> 14;
    int il = kk >> 5;
    int r  = kk & 31;
    int g  = r >> 1;
    int s  = r & 1;
    int i  = c * CI + il;
    const float* src = s ? sinA : cosA;
    float v = src[(o * I_DIM + i) * G_DIM + g];
    Bp[idx] = __float2bfloat16(v);
}

// ---------------------------------------------------------------------------
// Fused: features (cos/sin of x*freq) -> bf16 MFMA GEMM -> bias -> LayerNorm
// Grid: 256 blocks of 256 threads. Block tile: 64 n x 128 o. K = 4096.
// ---------------------------------------------------------------------------
__global__ __launch_bounds__(256) void fkan_main(
    const float* __restrict__ x,
    const __hip_bfloat16* __restrict__ Bp,
    const float* __restrict__ bias,
    const float* __restrict__ gamma,
    const float* __restrict__ beta,
    float* __restrict__ out)
{
    // LDS: A tile (64 x 136 bf16 = 17408 B) + B tile (128 x 136 bf16 = 34816 B)
    // Epilogue C tile (64 x 132 f32 = 33792 B) reuses the B region.
    __shared__ __align__(16) __bf16 smem[64 * A_STRIDE + 128 * B_STRIDE];
    __bf16* As = smem;
    __bf16* Bs = smem + 64 * A_STRIDE;
    float*  Cs = (float*)(smem + 64 * A_STRIDE);

    const int t    = threadIdx.x;
    const int lane = t & 63;
    const int wave = t >> 6;
    const int row16 = lane & 15;
    const int quad  = lane >> 4;
    const int n0 = blockIdx.x * BN;

    // feature-staging assignment: thread t -> (n = t/4, il = t%4)
    const int fn  = t >> 2;
    const int fil = t & 3;

    f32x4 acc[4][2];
#pragma unroll
    for (int mt = 0; mt < 4; ++mt)
#pragma unroll
        for (int ot = 0; ot < 2; ++ot)
            acc[mt][ot] = (f32x4){0.f, 0.f, 0.f, 0.f};

    for (int c = 0; c < NCHUNK; ++c) {
        // ---- stage A: compute 32 bf16 features for (fn, i = c*4+fil) ----
        {
            float xv = x[(size_t)(n0 + fn) * I_DIM + (c * CI + fil)];
            float s1, c1;
            __sincosf(xv, &s1, &c1);
            __align__(16) __bf16 feat[32];
            feat[0] = (__bf16)c1;
            feat[1] = (__bf16)s1;
            float ck = c1, sk = s1;
#pragma unroll
            for (int g = 1; g < 16; ++g) {
                float cn = ck * c1 - sk * s1;   // cos((g+1)x)
                float sn = sk * c1 + ck * s1;   // sin((g+1)x)
                feat[2 * g]     = (__bf16)cn;
                feat[2 * g + 1] = (__bf16)sn;
                ck = cn; sk = sn;
            }
            bf16x8* dst = (bf16x8*)(As + fn * A_STRIDE + fil * 32);
            const bf16x8* srcv = (const bf16x8*)feat;
#pragma unroll
            for (int j = 0; j < 4; ++j) dst[j] = srcv[j];
        }
        // ---- stage B: contiguous 32 KB chunk -> padded LDS rows ----
        {
            const uint4* src = (const uint4*)(Bp + (size_t)c * (O_DIM * KC));
#pragma unroll
            for (int it = 0; it < 8; ++it) {
                int idx = it * 256 + t;            // uint4 index, 16 per o-row
                uint4 v = src[idx];
                int o    = idx >> 4;
                int kk16 = idx & 15;
                *(uint4*)(Bs + o * B_STRIDE + kk16 * 8) = v;
            }
        }
        __syncthreads();

        // ---- MFMA: 4 ksteps x (4 m-tiles x 2 o-tiles) ----
#pragma unroll
        for (int ks = 0; ks < 4; ++ks) {
            bf16x8 a[4], b[2];
#pragma unroll
            for (int mt = 0; mt < 4; ++mt)
                a[mt] = *(const bf16x8*)(As + (mt * 16 + row16) * A_STRIDE + ks * 32 + quad * 8);
#pragma unroll
            for (int ot = 0; ot < 2; ++ot)
                b[ot] = *(const bf16x8*)(Bs + (wave * 32 + ot * 16 + row16) * B_STRIDE + ks * 32 + quad * 8);
#pragma unroll
            for (int mt = 0; mt < 4; ++mt)
#pragma unroll
                for (int ot = 0; ot < 2; ++ot)
                    acc[mt][ot] = __builtin_amdgcn_mfma_f32_16x16x32_bf16(
                        a[mt], b[ot], acc[mt][ot], 0, 0, 0);
        }
        __syncthreads();
    }

    // ---- epilogue: C -> LDS, bias + LayerNorm over O=128, store fp32 ----
    // C/D layout: col(o within 16) = lane&15, row(m within 16) = quad*4 + reg
#pragma unroll
    for (int mt = 0; mt < 4; ++mt)
#pragma unroll
        for (int ot = 0; ot < 2; ++ot)
#pragma unroll
            for (int r = 0; r < 4; ++r)
                Cs[(mt * 16 + quad * 4 + r) * C_STRIDE + wave * 32 + ot * 16 + row16] =
                    acc[mt][ot][r];
    __syncthreads();

    {
        const int r  = t >> 2;   // row within block (0..63)
        const int qt = t & 3;    // quarter of the O dim
        const float* crow = Cs + r * C_STRIDE + qt * 32;
        float vals[32];
        float sum = 0.f, sumsq = 0.f;
#pragma unroll
        for (int j = 0; j < 32; ++j) {
            float v = crow[j] + bias[qt * 32 + j];
            vals[j] = v;
            sum += v;
            sumsq += v * v;
        }
        // combine the 4 threads of this row (same wave, lanes differ in bits 0-1)
        sum   += __shfl_xor(sum, 1);   sum   += __shfl_xor(sum, 2);
        sumsq += __shfl_xor(sumsq, 1); sumsq += __shfl_xor(sumsq, 2);
        float mu  = sum * (1.0f / O_DIM);
        float var = sumsq * (1.0f / O_DIM) - mu * mu;
        float rstd = rsqrtf(var + 1e-5f);

        float* orow = out + (size_t)(n0 + r) * O_DIM + qt * 32;
#pragma unroll
        for (int jj = 0; jj < 8; ++jj) {
            float4 o4;
            o4.x = (vals[4 * jj + 0] - mu) * rstd * gamma[qt * 32 + 4 * jj + 0] + beta[qt * 32 + 4 * jj + 0];
            o4.y = (vals[4 * jj + 1] - mu) * rstd * gamma[qt * 32 + 4 * jj + 1] + beta[qt * 32 + 4 * jj + 1];
            o4.z = (vals[4 * jj + 2] - mu) * rstd * gamma[qt * 32 + 4 * jj + 2] + beta[qt * 32 + 4 * jj + 2];
            o4.w = (vals[4 * jj + 3] - mu) * rstd * gamma[qt * 32 + 4 * jj + 3] + beta[qt * 32 + 4 * jj + 3];
            *(float4*)(orow + 4 * jj) = o4;
        }
    }
}

extern "C" void kernel_launch(void* const* d_in, const int* in_sizes, int n_in,
                              void* d_out, int out_size, void* d_ws, size_t ws_size,
                              hipStream_t stream) {
    const float* x     = (const float*)d_in[0];
    const float* cosA  = (const float*)d_in[1];
    const float* sinA  = (const float*)d_in[2];
    const float* bias  = (const float*)d_in[3];
    const float* gamma = (const float*)d_in[4];
    const float* beta  = (const float*)d_in[5];
    float* out = (float*)d_out;

    __hip_bfloat16* Bp = (__hip_bfloat16*)d_ws;   // 1 MB: 32 chunks x 128 o x 128 k

    fkan_pack_b<<<dim3((NCHUNK * O_DIM * KC) / 256), dim3(256), 0, stream>>>(cosA, sinA, Bp);
    fkan_main<<<dim3(N_TOK / BN), dim3(256), 0, stream>>>(x, Bp, bias, gamma, beta, out);
}